// Round 1
// 1661.910 us; speedup vs baseline: 1.2563x; 1.2563x over previous
//
#include <hip/hip_runtime.h>
#include <cstdint>
#include <cstddef>

// ---------------------------------------------------------------------------
// CrossWindowAttention, MFMA version.
//   B1=2048, B2=8192 (ratio 4), N=64 tokens, C=128, H=4 heads, d=32.
//   All GEMM-shaped phases on v_mfma_f32_16x16x32_bf16 (fp32 accum).
//   Softmax + attn output stay fp32.
// Fragment layouts (gfx950, 16x16x32 bf16):
//   A: lane l holds A[lr][lg*8+e], lr=l&15, lg=l>>4, e=0..7 (8 contig k)
//   B: lane l holds B[lg*8+e][lr]
//   C/D: col = l&15, row = lg*4 + reg   [verified layout]
// LDS bf16 tiles XOR-swizzled: 16B-chunk' = chunk ^ (row & 7)  -> ds_read_b128
// conflict-free.
// ---------------------------------------------------------------------------

typedef float f32x4 __attribute__((ext_vector_type(4)));
typedef short s16x8 __attribute__((ext_vector_type(8)));

union U128 { uint4 u; s16x8 h; };

#define SM_Q   16384   // ushort offsets into smem
#define SM_K   24576
#define SM_VT  32768
#define SCALE  0.17677669529663687f

__device__ __forceinline__ uint32_t f2bf(float f) {
    union { float f; uint32_t i; } c; c.f = f;
    return (c.i + 0x7FFFu + ((c.i >> 16) & 1u)) >> 16;  // RNE
}
__device__ __forceinline__ uint32_t pk2(float a, float b) {
    return f2bf(a) | (f2bf(b) << 16);
}
__device__ __forceinline__ f32x4 mfma16(s16x8 a, s16x8 b, f32x4 c) {
    return __builtin_amdgcn_mfma_f32_16x16x32_bf16(a, b, c, 0, 0, 0);
}

// ---------------------------------------------------------------------------
// prep: w1/w2/pw -> bf16; bias gathered into per-(head,ntile,lane,reg,mtile)
// fragment order so the QK epilogue loads it as 4 coalesced float4 per tile.
// grid: 320 * 256 = 81920 = 16384 + 32768 + 16384 + 16384
// ---------------------------------------------------------------------------
__global__ __launch_bounds__(256) void prep_k(
    const float* __restrict__ w1, const float* __restrict__ w2,
    const float* __restrict__ pw, const float* __restrict__ rpb,
    const int* __restrict__ rel,
    ushort* __restrict__ w1b, ushort* __restrict__ w2b,
    ushort* __restrict__ pwb, float* __restrict__ bias_p)
{
    int i = blockIdx.x * 256 + threadIdx.x;
    if (i < 16384) {
        w1b[i] = (ushort)f2bf(w1[i]);
    } else if (i < 49152) {
        w2b[i - 16384] = (ushort)f2bf(w2[i - 16384]);
    } else if (i < 65536) {
        pwb[i - 49152] = (ushort)f2bf(pw[i - 49152]);
    } else {
        int j  = i - 65536;                 // (((h*4+nt)*64 + l)*4 + r)*4 + mt
        int mt = j & 3, r = (j >> 2) & 3, l = (j >> 4) & 63;
        int nt = (j >> 10) & 3, h = j >> 12;
        int n = nt * 16 + (l >> 4) * 4 + r;
        int m = mt * 16 + (l & 15);
        bias_p[j] = rpb[rel[n * 64 + m] * 4 + h];
    }
}

// ---------------------------------------------------------------------------
// q proj: q_ws[b] = (x1[b] @ w1^T + b1) * SCALE, stored bf16 PRE-SWIZZLED
// (exact LDS tile image) so fused_k stages it with a linear uint4 copy.
// ---------------------------------------------------------------------------
__global__ __launch_bounds__(256, 2) void q_proj_k(
    const float* __restrict__ x1, const ushort* __restrict__ w1b,
    const float* __restrict__ b1v, ushort* __restrict__ q_ws)
{
    __shared__ __align__(16) ushort xs[8192];
    const int tid = threadIdx.x, b = blockIdx.x;
    const int w = tid >> 6, l = tid & 63;
    const int lg = l >> 4, lr = l & 15;

    const float* xb = x1 + (size_t)b * 8192;
#pragma unroll
    for (int i = 0; i < 4; ++i) {
        int ch = tid + i * 256;              // chunk of 8 elems
        int row = ch >> 4, cc = ch & 15;
        float4 f0 = reinterpret_cast<const float4*>(xb)[ch * 2];
        float4 f1 = reinterpret_cast<const float4*>(xb)[ch * 2 + 1];
        uint4 p;
        p.x = pk2(f0.x, f0.y); p.y = pk2(f0.z, f0.w);
        p.z = pk2(f1.x, f1.y); p.w = pk2(f1.z, f1.w);
        *reinterpret_cast<uint4*>(&xs[row * 128 + ((cc ^ (row & 7)) * 8)]) = p;
    }

    U128 bfr[2][4];
#pragma unroll
    for (int ct = 0; ct < 2; ++ct)
#pragma unroll
        for (int kk = 0; kk < 4; ++kk)
            bfr[ct][kk].u = *reinterpret_cast<const uint4*>(
                w1b + (w * 32 + ct * 16 + lr) * 128 + kk * 32 + lg * 8);

    __syncthreads();

    f32x4 acc[4][2];
#pragma unroll
    for (int at = 0; at < 4; ++at)
#pragma unroll
        for (int ct = 0; ct < 2; ++ct) {
            f32x4 z = {0.f, 0.f, 0.f, 0.f};
            acc[at][ct] = z;
        }

#pragma unroll
    for (int kk = 0; kk < 4; ++kk) {
        U128 afr[4];
#pragma unroll
        for (int at = 0; at < 4; ++at) {
            int row = at * 16 + lr;
            afr[at].u = *reinterpret_cast<const uint4*>(
                &xs[row * 128 + (((kk * 4 + lg) ^ (row & 7)) * 8)]);
        }
#pragma unroll
        for (int at = 0; at < 4; ++at)
#pragma unroll
            for (int ct = 0; ct < 2; ++ct)
                acc[at][ct] = mfma16(afr[at].h, bfr[ct][kk].h, acc[at][ct]);
    }

    ushort* qb = q_ws + (size_t)b * 8192;
#pragma unroll
    for (int ct = 0; ct < 2; ++ct) {
        const int c = w * 32 + ct * 16 + lr;
        const float bias = b1v[c];
        const int csl = c >> 3, cof = c & 7;
#pragma unroll
        for (int at = 0; at < 4; ++at)
#pragma unroll
            for (int r = 0; r < 4; ++r) {
                int n = at * 16 + lg * 4 + r;
                qb[n * 128 + ((csl ^ (n & 7)) * 8) + cof] =
                    (ushort)f2bf((acc[at][ct][r] + bias) * SCALE);
            }
    }
}

// ---------------------------------------------------------------------------
// fused: per output batch b, loop r1: stage x2/q -> kv MFMA -> k/vT to LDS ->
// per-wave head attention (QK MFMA + bias, fp32 softmax, attn store, PV MFMA
// accumulating across r1 in C operand) -> out proj MFMA.
// LDS 81920 B -> 2 blocks/CU.
//   region A [0,16384) us : P[4][64x64]   (xs [64][128] aliases [0,8192))
//   SM_Q  [16384,24576)   : q  [64][128]
//   SM_K  [24576,32768)   : k  [64][128]
//   SM_VT [32768,40960)   : vT [128][64]  (row = (c-128) = h*32+dh)
// ---------------------------------------------------------------------------
__global__ __launch_bounds__(256, 2) void fused_k(
    const float* __restrict__ x2,  const ushort* __restrict__ w2b,
    const float* __restrict__ b2v, const ushort* __restrict__ pwb,
    const float* __restrict__ pb,  const ushort* __restrict__ q_ws,
    const float* __restrict__ bias_p,
    float* __restrict__ out_x, float* __restrict__ out_attn)
{
    __shared__ __align__(16) ushort smem[40960];
    const int tid = threadIdx.x, b = blockIdx.x;
    const int w = tid >> 6, l = tid & 63;
    const int lg = l >> 4, lr = l & 15;
    const int h = w;                       // wave == head in attention phase

    f32x4 accPV[4][2];
#pragma unroll
    for (int at = 0; at < 4; ++at)
#pragma unroll
        for (int dt = 0; dt < 2; ++dt) {
            f32x4 z = {0.f, 0.f, 0.f, 0.f};
            accPV[at][dt] = z;
        }

    // r1-invariant kv bias (4 scalars per lane)
    float bv[4];
#pragma unroll
    for (int ct = 0; ct < 4; ++ct) bv[ct] = b2v[64 * w + ct * 16 + lr];

#pragma unroll 1
    for (int r1 = 0; r1 < 4; ++r1) {
        const int b2  = b * 4 + r1;
        const int b1q = b2 & 2047;

        // ---- stage: x2 -> bf16 swizzled xs;  q tile -> linear copy ----
        const float*  xb = x2   + (size_t)b2  * 8192;
        const ushort* qb = q_ws + (size_t)b1q * 8192;
#pragma unroll
        for (int i = 0; i < 4; ++i) {
            int ch = tid + i * 256;
            int row = ch >> 4, cc = ch & 15;
            float4 f0 = reinterpret_cast<const float4*>(xb)[ch * 2];
            float4 f1 = reinterpret_cast<const float4*>(xb)[ch * 2 + 1];
            uint4 p;
            p.x = pk2(f0.x, f0.y); p.y = pk2(f0.z, f0.w);
            p.z = pk2(f1.x, f1.y); p.w = pk2(f1.z, f1.w);
            *reinterpret_cast<uint4*>(&smem[row * 128 + ((cc ^ (row & 7)) * 8)]) = p;
            reinterpret_cast<uint4*>(&smem[SM_Q])[ch] =
                reinterpret_cast<const uint4*>(qb)[ch];
        }
        __syncthreads();

        // ---- kv proj: wave w owns output cols [64w, 64w+64) ----
        f32x4 akv[4][4];
#pragma unroll
        for (int at = 0; at < 4; ++at)
#pragma unroll
            for (int ct = 0; ct < 4; ++ct) {
                f32x4 z = {0.f, 0.f, 0.f, 0.f};
                akv[at][ct] = z;
            }
        U128 bkv[4][4];
#pragma unroll
        for (int ct = 0; ct < 4; ++ct)
#pragma unroll
            for (int kk = 0; kk < 4; ++kk)
                bkv[ct][kk].u = *reinterpret_cast<const uint4*>(
                    w2b + (64 * w + ct * 16 + lr) * 128 + kk * 32 + lg * 8);
#pragma unroll
        for (int kk = 0; kk < 4; ++kk) {
            U128 afr[4];
#pragma unroll
            for (int at = 0; at < 4; ++at) {
                int row = at * 16 + lr;
                afr[at].u = *reinterpret_cast<const uint4*>(
                    &smem[row * 128 + (((kk * 4 + lg) ^ (row & 7)) * 8)]);
            }
#pragma unroll
            for (int at = 0; at < 4; ++at)
#pragma unroll
                for (int ct = 0; ct < 4; ++ct)
                    akv[at][ct] = mfma16(afr[at].h, bkv[ct][kk].h, akv[at][ct]);
        }

        // ---- epilogue: k rows (waves 0,1) / transposed v (waves 2,3) ----
        if (w < 2) {
#pragma unroll
            for (int ct = 0; ct < 4; ++ct) {
                int c = 64 * w + ct * 16 + lr;
                int csl = c >> 3, cof = c & 7;
#pragma unroll
                for (int at = 0; at < 4; ++at)
#pragma unroll
                    for (int r = 0; r < 4; ++r) {
                        int n = at * 16 + lg * 4 + r;
                        smem[SM_K + n * 128 + ((csl ^ (n & 7)) * 8) + cof] =
                            (ushort)f2bf(akv[at][ct][r] + bv[ct]);
                    }
            }
        } else {
#pragma unroll
            for (int ct = 0; ct < 4; ++ct) {
                int cv = 64 * (w - 2) + ct * 16 + lr;      // 0..127 = h*32+dh
                int vsw = cv & 7;
#pragma unroll
                for (int at = 0; at < 4; ++at)
#pragma unroll
                    for (int r = 0; r < 4; ++r) {
                        int m = at * 16 + lg * 4 + r;
                        smem[SM_VT + cv * 64 + (((m >> 3) ^ vsw) * 8) + (m & 7)] =
                            (ushort)f2bf(akv[at][ct][r] + bv[ct]);
                    }
            }
        }
        __syncthreads();

        // ---- QK^T (K=32 -> one MFMA per 16x16 tile) ----
        U128 qf[4], kf[4];
#pragma unroll
        for (int t = 0; t < 4; ++t) {
            int row = t * 16 + lr;
            int sl = ((h * 4 + lg) ^ (row & 7)) * 8;
            qf[t].u = *reinterpret_cast<const uint4*>(&smem[SM_Q + row * 128 + sl]);
            kf[t].u = *reinterpret_cast<const uint4*>(&smem[SM_K + row * 128 + sl]);
        }
        f32x4 aq[4][4];
        {
            f32x4 z4 = {0.f, 0.f, 0.f, 0.f};
#pragma unroll
            for (int at = 0; at < 4; ++at)
#pragma unroll
                for (int mt = 0; mt < 4; ++mt)
                    aq[at][mt] = mfma16(qf[at].h, kf[mt].h, z4);
        }

        // ---- bias + softmax (fp32), attn store, P -> bf16 LDS ----
        float* ab = out_attn + (((size_t)b2 * 4 + h) << 12);
#pragma unroll
        for (int at = 0; at < 4; ++at) {
            const float* bpp = bias_p + ((size_t)((h * 4 + at) * 64 + l)) * 16;
            float4 bb0 = *reinterpret_cast<const float4*>(bpp);
            float4 bb1 = *reinterpret_cast<const float4*>(bpp + 4);
            float4 bb2 = *reinterpret_cast<const float4*>(bpp + 8);
            float4 bb3 = *reinterpret_cast<const float4*>(bpp + 12);
            aq[at][0][0] += bb0.x; aq[at][1][0] += bb0.y; aq[at][2][0] += bb0.z; aq[at][3][0] += bb0.w;
            aq[at][0][1] += bb1.x; aq[at][1][1] += bb1.y; aq[at][2][1] += bb1.z; aq[at][3][1] += bb1.w;
            aq[at][0][2] += bb2.x; aq[at][1][2] += bb2.y; aq[at][2][2] += bb2.z; aq[at][3][2] += bb2.w;
            aq[at][0][3] += bb3.x; aq[at][1][3] += bb3.y; aq[at][2][3] += bb3.z; aq[at][3][3] += bb3.w;

#pragma unroll
            for (int r = 0; r < 4; ++r) {
                float v0 = aq[at][0][r], v1 = aq[at][1][r];
                float v2 = aq[at][2][r], v3 = aq[at][3][r];
                float mx = fmaxf(fmaxf(v0, v1), fmaxf(v2, v3));
                mx = fmaxf(mx, __shfl_xor(mx, 1));
                mx = fmaxf(mx, __shfl_xor(mx, 2));
                mx = fmaxf(mx, __shfl_xor(mx, 4));
                mx = fmaxf(mx, __shfl_xor(mx, 8));
                float e0 = __expf(v0 - mx), e1 = __expf(v1 - mx);
                float e2 = __expf(v2 - mx), e3 = __expf(v3 - mx);
                float s = e0 + e1 + e2 + e3;
                s += __shfl_xor(s, 1);
                s += __shfl_xor(s, 2);
                s += __shfl_xor(s, 4);
                s += __shfl_xor(s, 8);
                float inv = 1.0f / s;
                e0 *= inv; e1 *= inv; e2 *= inv; e3 *= inv;

                int n = at * 16 + lg * 4 + r;
                ab[n * 64 +      lr] = e0;
                ab[n * 64 + 16 + lr] = e1;
                ab[n * 64 + 32 + lr] = e2;
                ab[n * 64 + 48 + lr] = e3;

                int pbase = h * 4096 + n * 64;    // P aliases xs (dead now)
                int nsw = n & 7, l7 = lr & 7, lh = lr >> 3;
                smem[pbase + (((0 + lh) ^ nsw) * 8) + l7] = (ushort)f2bf(e0);
                smem[pbase + (((2 + lh) ^ nsw) * 8) + l7] = (ushort)f2bf(e1);
                smem[pbase + (((4 + lh) ^ nsw) * 8) + l7] = (ushort)f2bf(e2);
                smem[pbase + (((6 + lh) ^ nsw) * 8) + l7] = (ushort)f2bf(e3);
            }
        }

        // ---- PV: accPV += P @ v   (same-wave LDS RAW, in-order) ----
#pragma unroll
        for (int kk = 0; kk < 2; ++kk) {
            U128 pf[4], vf[2];
#pragma unroll
            for (int at = 0; at < 4; ++at) {
                int row = at * 16 + lr;
                pf[at].u = *reinterpret_cast<const uint4*>(
                    &smem[h * 4096 + row * 64 + (((kk * 4 + lg) ^ (row & 7)) * 8)]);
            }
#pragma unroll
            for (int dt = 0; dt < 2; ++dt) {
                int row = h * 32 + dt * 16 + lr;
                vf[dt].u = *reinterpret_cast<const uint4*>(
                    &smem[SM_VT + row * 64 + (((kk * 4 + lg) ^ (row & 7)) * 8)]);
            }
#pragma unroll
            for (int at = 0; at < 4; ++at)
#pragma unroll
                for (int dt = 0; dt < 2; ++dt)
                    accPV[at][dt] = mfma16(pf[at].h, vf[dt].h, accPV[at][dt]);
        }
        __syncthreads();
    } // r1

    // ---- out proj: ys(bf16, swizzled) -> x = ys @ pw^T + pb ----
#pragma unroll
    for (int at = 0; at < 4; ++at)
#pragma unroll
        for (int dt = 0; dt < 2; ++dt) {
            int cg = h * 32 + dt * 16 + lr;
            int csl = cg >> 3, cof = cg & 7;
#pragma unroll
            for (int r = 0; r < 4; ++r) {
                int n = at * 16 + lg * 4 + r;
                smem[n * 128 + ((csl ^ (n & 7)) * 8) + cof] =
                    (ushort)f2bf(accPV[at][dt][r]);
            }
        }
    __syncthreads();

    f32x4 ap[4][2];
#pragma unroll
    for (int at = 0; at < 4; ++at)
#pragma unroll
        for (int ct = 0; ct < 2; ++ct) {
            f32x4 z = {0.f, 0.f, 0.f, 0.f};
            ap[at][ct] = z;
        }
    U128 bpf[2][4];
#pragma unroll
    for (int ct = 0; ct < 2; ++ct)
#pragma unroll
        for (int kk = 0; kk < 4; ++kk)
            bpf[ct][kk].u = *reinterpret_cast<const uint4*>(
                pwb + (w * 32 + ct * 16 + lr) * 128 + kk * 32 + lg * 8);
#pragma unroll
    for (int kk = 0; kk < 4; ++kk) {
        U128 af[4];
#pragma unroll
        for (int at = 0; at < 4; ++at) {
            int row = at * 16 + lr;
            af[at].u = *reinterpret_cast<const uint4*>(
                &smem[row * 128 + (((kk * 4 + lg) ^ (row & 7)) * 8)]);
        }
#pragma unroll
        for (int at = 0; at < 4; ++at)
#pragma unroll
            for (int ct = 0; ct < 2; ++ct)
                ap[at][ct] = mfma16(af[at].h, bpf[ct][kk].h, ap[at][ct]);
    }

    float* ob = out_x + (size_t)b * 8192;
#pragma unroll
    for (int ct = 0; ct < 2; ++ct) {
        int c = w * 32 + ct * 16 + lr;
        float bias = pb[c];
#pragma unroll
        for (int at = 0; at < 4; ++at)
#pragma unroll
            for (int r = 0; r < 4; ++r) {
                int n = at * 16 + lg * 4 + r;
                ob[n * 128 + c] = ap[at][ct][r] + bias;
            }
    }
}

// ---------------------------------------------------------------------------
extern "C" void kernel_launch(void* const* d_in, const int* in_sizes, int n_in,
                              void* d_out, int out_size, void* d_ws, size_t ws_size,
                              hipStream_t stream) {
    (void)in_sizes; (void)n_in; (void)out_size; (void)ws_size;
    const float* x1  = (const float*)d_in[0];
    const float* x2  = (const float*)d_in[1];
    const float* w1  = (const float*)d_in[2];
    const float* b1v = (const float*)d_in[3];
    const float* w2  = (const float*)d_in[4];
    const float* b2v = (const float*)d_in[5];
    const float* pw  = (const float*)d_in[6];
    const float* pb  = (const float*)d_in[7];
    const float* rpb = (const float*)d_in[8];
    const int*   rel = (const int*)d_in[9];
    // d_in[10] = num_heads (compile-time constant 4)

    float* out_x    = (float*)d_out;
    float* out_attn = out_x + (size_t)2048 * 64 * 128;   // x first, then attn

    // workspace: q_ws bf16 (pre-swizzled tiles) + bf16 weights + packed bias
    ushort* q_ws = (ushort*)d_ws;                 // 2048*8192 ushort = 33.5 MB
    ushort* w1b  = q_ws + (size_t)2048 * 8192;    // 16384
    ushort* w2b  = w1b + 16384;                   // 32768
    ushort* pwb  = w2b + 32768;                   // 16384
    float*  bias_p = (float*)(pwb + 16384);       // 16384 f32 (64 KB)

    prep_k  <<<320,  256, 0, stream>>>(w1, w2, pw, rpb, rel, w1b, w2b, pwb, bias_p);
    q_proj_k<<<2048, 256, 0, stream>>>(x1, w1b, b1v, q_ws);
    fused_k <<<2048, 256, 0, stream>>>(x2, w2b, b2v, pwb, pb, q_ws, bias_p,
                                       out_x, out_attn);
}